// Round 1
// baseline (167.735 us; speedup 1.0000x reference)
//
#include <hip/hip_runtime.h>
#include <math.h>

// Problem constants (fixed by setup_inputs): B=8, C=4, H=W=64, K=8192
#define N_POINTS 32768   // B*H*W
#define KCODES   8192
#define HW       4096
#define CHW      16384
#define NSEG     8
#define SEGLEN   (KCODES / NSEG)

// ws layout (bytes, 16B-aligned offsets)
//   z4    float4[32768]      @ 0         (z vector per point)
//   z2    float [32768]      @ 524288    (|z|^2, numpy rounding order)
//   cb2   float4[8192]       @ 655360    (2*codebook — exact doubling)
//   cbn   float [8192]       @ 786432    (|c|^2, numpy rounding order)
//   bestS float [8][32768]   @ 819200
//   bestI int   [8][32768]   @ 1867776
// total ~2.8 MB

#define WS_Z4    0
#define WS_Z2    524288
#define WS_CB2   655360
#define WS_CBN   786432
#define WS_BESTS 819200
#define WS_BESTI 1867776

// ---------------- Kernel A: prep (conv z + norms, codebook transform) ------
__global__ __launch_bounds__(256) void vq_prep(
    const float* __restrict__ ze, const float* __restrict__ w,
    const float* __restrict__ bias, const float* __restrict__ cb,
    float4* __restrict__ z4, float* __restrict__ z2,
    float4* __restrict__ cb2, float* __restrict__ cbn) {
  int t = blockIdx.x * 256 + threadIdx.x;
  if (blockIdx.x < 128) {
    // one thread per spatial point: z[o] = sum_c in[c]*w[o][c] + b[o]
    int n = t;                       // 0..32767
    int b = n >> 12, hw = n & 4095;
    const float* p = ze + b * CHW + hw;
    float x0 = p[0], x1 = p[HW], x2 = p[2 * HW], x3 = p[3 * HW];
    float zo[4];
#pragma unroll
    for (int o = 0; o < 4; ++o) {
      // numpy einsum (optimize=False): sequential c-order, no FMA
      float acc = __fmul_rn(x0, w[o * 4 + 0]);
      acc = __fadd_rn(acc, __fmul_rn(x1, w[o * 4 + 1]));
      acc = __fadd_rn(acc, __fmul_rn(x2, w[o * 4 + 2]));
      acc = __fadd_rn(acc, __fmul_rn(x3, w[o * 4 + 3]));
      zo[o] = __fadd_rn(acc, bias[o]);
    }
    z4[n] = make_float4(zo[0], zo[1], zo[2], zo[3]);
    float s = __fmul_rn(zo[0], zo[0]);
    s = __fadd_rn(s, __fmul_rn(zo[1], zo[1]));
    s = __fadd_rn(s, __fmul_rn(zo[2], zo[2]));
    s = __fadd_rn(s, __fmul_rn(zo[3], zo[3]));
    z2[n] = s;
  } else {
    int k = t - N_POINTS;            // 0..8191
    float c0 = cb[k * 4 + 0], c1 = cb[k * 4 + 1];
    float c2 = cb[k * 4 + 2], c3 = cb[k * 4 + 3];
    // doubling is exact (power of 2): sum of 2*z*c == 2*(sum z*c) bitwise
    cb2[k] = make_float4(2.f * c0, 2.f * c1, 2.f * c2, 2.f * c3);
    float s = __fmul_rn(c0, c0);
    s = __fadd_rn(s, __fmul_rn(c1, c1));
    s = __fadd_rn(s, __fmul_rn(c2, c2));
    s = __fadd_rn(s, __fmul_rn(c3, c3));
    cbn[k] = s;
  }
}

// ---------------- Kernel B: brute-force argmin scan over a segment ---------
__global__ __launch_bounds__(256) void vq_scan(
    const float4* __restrict__ z4, const float* __restrict__ z2,
    const float4* __restrict__ cb2, const float* __restrict__ cbn,
    float* __restrict__ bestS, int* __restrict__ bestI) {
  int n = blockIdx.x * 256 + threadIdx.x;   // point id
  int seg = blockIdx.y;                      // codebook segment
  float4 z = z4[n];
  float zz = z2[n];
  float best = INFINITY;
  int bidx = 0;
  int k0 = seg * SEGLEN;
#pragma unroll 4
  for (int k = k0; k < k0 + SEGLEN; ++k) {
    // k is wave-uniform -> cb2/cbn loads are scalar (SMEM) candidates
    float4 c = cb2[k];
    // dot2 = 2*dot with numpy's sequential rounding order (see doubling note)
    float d = __fmul_rn(z.x, c.x);
    d = __fadd_rn(d, __fmul_rn(z.y, c.y));
    d = __fadd_rn(d, __fmul_rn(z.z, c.z));
    d = __fadd_rn(d, __fmul_rn(z.w, c.w));
    // ref: (|z|^2 - 2*dot) + |c|^2, left-to-right
    float s = __fadd_rn(__fsub_rn(zz, d), cbn[k]);
    if (s < best) { best = s; bidx = k; }    // strict < : first-min wins
  }
  bestS[seg * N_POINTS + n] = best;
  bestI[seg * N_POINTS + n] = bidx;
}

// ---------------- Kernel C: cross-segment reduce, gather, loss, output -----
__global__ __launch_bounds__(256) void vq_finish(
    const float* __restrict__ cb, const float4* __restrict__ z4,
    const float* __restrict__ bestS, const int* __restrict__ bestI,
    float* __restrict__ out) {
  int n = blockIdx.x * 256 + threadIdx.x;
  float best = INFINITY;
  int bidx = 0;
#pragma unroll
  for (int s = 0; s < NSEG; ++s) {           // ascending segment order:
    float v = bestS[s * N_POINTS + n];       // strict < keeps earliest k on
    int i = bestI[s * N_POINTS + n];         // bitwise ties (np.argmin semantics)
    if (v < best) { best = v; bidx = i; }
  }
  float c0 = cb[bidx * 4 + 0], c1 = cb[bidx * 4 + 1];
  float c2 = cb[bidx * 4 + 2], c3 = cb[bidx * 4 + 3];
  int b = n >> 12, hw = n & 4095;
  float* o = out + b * CHW + hw;
  o[0] = c0; o[HW] = c1; o[2 * HW] = c2; o[3 * HW] = c3;  // bit-exact gather
  // loss terms
  float4 z = z4[n];
  float d0 = c0 - z.x, d1 = c1 - z.y, d2 = c2 - z.z, d3 = c3 - z.w;
  float e = d0 * d0 + d1 * d1 + d2 * d2 + d3 * d3;
  // wave reduce (64 lanes) then cross-wave via LDS
#pragma unroll
  for (int off = 32; off > 0; off >>= 1) e += __shfl_down(e, off, 64);
  __shared__ float sred[4];
  if ((threadIdx.x & 63) == 0) sred[threadIdx.x >> 6] = e;
  __syncthreads();
  if (threadIdx.x == 0) {
    float t = (sred[0] + sred[1]) + (sred[2] + sred[3]);
    // q_loss = (1 + BETA) * mean over 131072 elements
    atomicAdd(out + (N_POINTS * 4), t * (1.25f / 131072.f));
  }
}

extern "C" void kernel_launch(void* const* d_in, const int* in_sizes, int n_in,
                              void* d_out, int out_size, void* d_ws, size_t ws_size,
                              hipStream_t stream) {
  const float* ze   = (const float*)d_in[0];  // z_e_in [8,4,64,64]
  const float* w    = (const float*)d_in[1];  // pq_w [4,4]
  const float* bias = (const float*)d_in[2];  // pq_b [4]
  const float* cb   = (const float*)d_in[3];  // codebook [8192,4]

  char* ws = (char*)d_ws;
  float4* z4   = (float4*)(ws + WS_Z4);
  float*  z2   = (float*)(ws + WS_Z2);
  float4* cb2  = (float4*)(ws + WS_CB2);
  float*  cbn  = (float*)(ws + WS_CBN);
  float* bestS = (float*)(ws + WS_BESTS);
  int*   bestI = (int*)(ws + WS_BESTI);
  float* out = (float*)d_out;

  // d_out is re-poisoned before every launch: zero the loss scalar slot
  hipMemsetAsync(out + (N_POINTS * 4), 0, sizeof(float), stream);

  vq_prep<<<160, 256, 0, stream>>>(ze, w, bias, cb, z4, z2, cb2, cbn);
  vq_scan<<<dim3(128, NSEG), 256, 0, stream>>>(z4, z2, cb2, cbn, bestS, bestI);
  vq_finish<<<128, 256, 0, stream>>>(cb, z4, bestS, bestI, out);
}

// Round 2
// 147.295 us; speedup vs baseline: 1.1388x; 1.1388x over previous
//
#include <hip/hip_runtime.h>
#include <math.h>

// Problem constants (fixed by setup_inputs): B=8, C=4, H=W=64, K=8192
#define N_POINTS 32768   // B*H*W
#define KCODES   8192
#define HW       4096
#define CHW      16384
#define NSEG     16
#define SEGLEN   (KCODES / NSEG)   // 512

// ws layout (bytes):
//   cb2    float4[8192]  @ 0        (2*codebook — exact doubling)
//   cbn    float [8192]  @ 131072   (|c|^2, numpy rounding order)
//   packed u64   [32768] @ 163840   ((sortable(best_d2)<<32)|best_k per point)
#define WS_CB2    0
#define WS_CBN    131072
#define WS_PACKED 163840

// Bit-exact conv z = W x + b, numpy sequential c-order, no FMA contraction.
__device__ __forceinline__ void compute_z(
    const float* __restrict__ ze, const float* __restrict__ w,
    const float* __restrict__ bias, int n, float zo[4], float& zz) {
  int b = n >> 12, hw = n & 4095;
  const float* p = ze + b * CHW + hw;
  float x0 = p[0], x1 = p[HW], x2 = p[2 * HW], x3 = p[3 * HW];
#pragma unroll
  for (int o = 0; o < 4; ++o) {
    float acc = __fmul_rn(x0, w[o * 4 + 0]);
    acc = __fadd_rn(acc, __fmul_rn(x1, w[o * 4 + 1]));
    acc = __fadd_rn(acc, __fmul_rn(x2, w[o * 4 + 2]));
    acc = __fadd_rn(acc, __fmul_rn(x3, w[o * 4 + 3]));
    zo[o] = __fadd_rn(acc, bias[o]);
  }
  float s = __fmul_rn(zo[0], zo[0]);
  s = __fadd_rn(s, __fmul_rn(zo[1], zo[1]));
  s = __fadd_rn(s, __fmul_rn(zo[2], zo[2]));
  s = __fadd_rn(s, __fmul_rn(zo[3], zo[3]));
  zz = s;
}

// ---------------- Kernel P: init packed + codebook transform + loss zero ---
__global__ __launch_bounds__(256) void vq_init(
    const float* __restrict__ cb, float4* __restrict__ cb2,
    float* __restrict__ cbn, unsigned long long* __restrict__ packed,
    float* __restrict__ out) {
  int t = blockIdx.x * 256 + threadIdx.x;   // grid covers 32768
  packed[t] = 0xFFFFFFFFFFFFFFFFull;        // ws is re-poisoned every call
  if (t < KCODES) {
    float c0 = cb[t * 4 + 0], c1 = cb[t * 4 + 1];
    float c2 = cb[t * 4 + 2], c3 = cb[t * 4 + 3];
    // doubling by 2 is exact: sum(2*z*c) == 2*sum(z*c) bitwise
    cb2[t] = make_float4(2.f * c0, 2.f * c1, 2.f * c2, 2.f * c3);
    float s = __fmul_rn(c0, c0);
    s = __fadd_rn(s, __fmul_rn(c1, c1));
    s = __fadd_rn(s, __fmul_rn(c2, c2));
    s = __fadd_rn(s, __fmul_rn(c3, c3));
    cbn[t] = s;
  }
  if (t == 0) out[N_POINTS * 4] = 0.f;      // zero the q_loss slot
}

// ---------------- Kernel S: fused conv + argmin scan over a segment --------
__global__ __launch_bounds__(256, 8) void vq_scan(
    const float* __restrict__ ze, const float* __restrict__ w,
    const float* __restrict__ bias, const float4* __restrict__ cb2,
    const float* __restrict__ cbn, unsigned long long* __restrict__ packed) {
  int n = blockIdx.x * 256 + threadIdx.x;   // point id
  int seg = blockIdx.y;                     // codebook segment
  float z[4], zz;
  compute_z(ze, w, bias, n, z, zz);
  int k0 = seg * SEGLEN;
  float best = INFINITY;
  int bidx = k0;
#pragma unroll 8
  for (int k = k0; k < k0 + SEGLEN; ++k) {
    // k is wave-uniform -> cb2/cbn loads lower to s_load batches
    float4 c = cb2[k];
    // 2*dot with numpy's sequential rounding order
    float d = __fmul_rn(z[0], c.x);
    d = __fadd_rn(d, __fmul_rn(z[1], c.y));
    d = __fadd_rn(d, __fmul_rn(z[2], c.z));
    d = __fadd_rn(d, __fmul_rn(z[3], c.w));
    // ref: (|z|^2 - 2*dot) + |c|^2, left-to-right
    float s = __fadd_rn(__fsub_rn(zz, d), cbn[k]);
    if (s < best) { best = s; bidx = k; }   // strict < : first-min wins
  }
  // pack (sortable float, k): u64 min == (min value, then min k)
  unsigned int u = __float_as_uint(best);
  unsigned int sortable = (u & 0x80000000u) ? ~u : (u | 0x80000000u);
  unsigned long long key = ((unsigned long long)sortable << 32) | (unsigned int)bidx;
  atomicMin(&packed[n], key);
}

// ---------------- Kernel F: decode, gather, latent write, loss -------------
__global__ __launch_bounds__(256) void vq_finish(
    const float* __restrict__ ze, const float* __restrict__ w,
    const float* __restrict__ bias, const float* __restrict__ cb,
    const unsigned long long* __restrict__ packed, float* __restrict__ out) {
  int n = blockIdx.x * 256 + threadIdx.x;
  int bidx = (unsigned int)(packed[n] & 0xFFFFFFFFull);
  float4 c = ((const float4*)cb)[bidx];     // bit-exact gather (16B aligned)
  int b = n >> 12, hw = n & 4095;
  float* o = out + b * CHW + hw;
  o[0] = c.x; o[HW] = c.y; o[2 * HW] = c.z; o[3 * HW] = c.w;
  float z[4], zz;
  compute_z(ze, w, bias, n, z, zz);
  float d0 = c.x - z[0], d1 = c.y - z[1], d2 = c.z - z[2], d3 = c.w - z[3];
  float e = d0 * d0 + d1 * d1 + d2 * d2 + d3 * d3;
#pragma unroll
  for (int off = 32; off > 0; off >>= 1) e += __shfl_down(e, off, 64);
  __shared__ float sred[4];
  if ((threadIdx.x & 63) == 0) sred[threadIdx.x >> 6] = e;
  __syncthreads();
  if (threadIdx.x == 0) {
    float t = (sred[0] + sred[1]) + (sred[2] + sred[3]);
    // q_loss = (1 + BETA) * mean over 131072 elements
    atomicAdd(out + (N_POINTS * 4), t * (1.25f / 131072.f));
  }
}

extern "C" void kernel_launch(void* const* d_in, const int* in_sizes, int n_in,
                              void* d_out, int out_size, void* d_ws, size_t ws_size,
                              hipStream_t stream) {
  const float* ze   = (const float*)d_in[0];  // z_e_in [8,4,64,64]
  const float* w    = (const float*)d_in[1];  // pq_w [4,4]
  const float* bias = (const float*)d_in[2];  // pq_b [4]
  const float* cb   = (const float*)d_in[3];  // codebook [8192,4]

  char* ws = (char*)d_ws;
  float4* cb2 = (float4*)(ws + WS_CB2);
  float*  cbn = (float*)(ws + WS_CBN);
  unsigned long long* packed = (unsigned long long*)(ws + WS_PACKED);
  float* out = (float*)d_out;

  vq_init<<<128, 256, 0, stream>>>(cb, cb2, cbn, packed, out);
  vq_scan<<<dim3(128, NSEG), 256, 0, stream>>>(ze, w, bias, cb2, cbn, packed);
  vq_finish<<<128, 256, 0, stream>>>(ze, w, bias, cb, packed, out);
}

// Round 3
// 142.732 us; speedup vs baseline: 1.1752x; 1.0320x over previous
//
#include <hip/hip_runtime.h>
#include <math.h>

// Problem constants (fixed by setup_inputs): B=8, C=4, H=W=64, K=8192
#define N_POINTS 32768   // B*H*W
#define KCODES   8192
#define HW       4096
#define CHW      16384
#define NSEG     32
#define SEGLEN   (KCODES / NSEG)   // 256
#define PPT      4                 // points per thread in vq_scan
#define PTILE    (256 * PPT)       // 1024 points per block

// ws layout (bytes):
//   cb2    float4[8192]  @ 0        (2*codebook — exact doubling)
//   cbn    float [8192]  @ 131072   (|c|^2, numpy rounding order; 16B aligned)
//   packed u64   [32768] @ 163840   ((sortable(best_d2)<<32)|best_k per point)
#define WS_CB2    0
#define WS_CBN    131072
#define WS_PACKED 163840

// Bit-exact conv z = W x + b, numpy sequential c-order, no FMA contraction.
__device__ __forceinline__ void compute_z(
    const float* __restrict__ ze, const float* __restrict__ w,
    const float* __restrict__ bias, int n, float zo[4], float& zz) {
  int b = n >> 12, hw = n & 4095;
  const float* p = ze + b * CHW + hw;
  float x0 = p[0], x1 = p[HW], x2 = p[2 * HW], x3 = p[3 * HW];
#pragma unroll
  for (int o = 0; o < 4; ++o) {
    float acc = __fmul_rn(x0, w[o * 4 + 0]);
    acc = __fadd_rn(acc, __fmul_rn(x1, w[o * 4 + 1]));
    acc = __fadd_rn(acc, __fmul_rn(x2, w[o * 4 + 2]));
    acc = __fadd_rn(acc, __fmul_rn(x3, w[o * 4 + 3]));
    zo[o] = __fadd_rn(acc, bias[o]);
  }
  float s = __fmul_rn(zo[0], zo[0]);
  s = __fadd_rn(s, __fmul_rn(zo[1], zo[1]));
  s = __fadd_rn(s, __fmul_rn(zo[2], zo[2]));
  s = __fadd_rn(s, __fmul_rn(zo[3], zo[3]));
  zz = s;
}

// ---------------- Kernel P: init packed + codebook transform + loss zero ---
__global__ __launch_bounds__(256) void vq_init(
    const float* __restrict__ cb, float4* __restrict__ cb2,
    float* __restrict__ cbn, unsigned long long* __restrict__ packed,
    float* __restrict__ out) {
  int t = blockIdx.x * 256 + threadIdx.x;   // grid covers 32768
  packed[t] = 0xFFFFFFFFFFFFFFFFull;        // ws is re-poisoned every call
  if (t < KCODES) {
    float c0 = cb[t * 4 + 0], c1 = cb[t * 4 + 1];
    float c2 = cb[t * 4 + 2], c3 = cb[t * 4 + 3];
    // doubling by 2 is exact: sum(2*z*c) == 2*sum(z*c) bitwise
    cb2[t] = make_float4(2.f * c0, 2.f * c1, 2.f * c2, 2.f * c3);
    float s = __fmul_rn(c0, c0);
    s = __fadd_rn(s, __fmul_rn(c1, c1));
    s = __fadd_rn(s, __fmul_rn(c2, c2));
    s = __fadd_rn(s, __fmul_rn(c3, c3));
    cbn[t] = s;
  }
  if (t == 0) out[N_POINTS * 4] = 0.f;      // zero the q_loss slot
}

// ---------------- Kernel S: fused conv + argmin scan, register-blocked -----
// Each thread: P=4 points in registers, codes streamed in chunks of 4.
// Loads amortize over 16 pair-computations; ~12.5 VALU lane-ops/pair.
__global__ __launch_bounds__(256) void vq_scan(
    const float* __restrict__ ze, const float* __restrict__ w,
    const float* __restrict__ bias, const float4* __restrict__ cb2,
    const float* __restrict__ cbn, unsigned long long* __restrict__ packed) {
  int tid = threadIdx.x;
  int n0 = blockIdx.x * PTILE + tid;        // points n0 + 256*p, coalesced
  float z[PPT][4], zz[PPT], best[PPT];
  int bidx[PPT];
#pragma unroll
  for (int p = 0; p < PPT; ++p) {
    compute_z(ze, w, bias, n0 + 256 * p, z[p], zz[p]);
    best[p] = INFINITY;
    bidx[p] = 0;
  }
  int k0 = blockIdx.y * SEGLEN;
  const float4* cp = cb2 + k0;
  const float4* np = (const float4*)(cbn + k0);   // 16B aligned, k0 % 4 == 0
  for (int kc = 0; kc < SEGLEN; kc += 4) {
    float4 c[4];
    c[0] = cp[kc + 0]; c[1] = cp[kc + 1];
    c[2] = cp[kc + 2]; c[3] = cp[kc + 3];
    float4 cn4 = np[kc >> 2];
    float cnr[4] = {cn4.x, cn4.y, cn4.z, cn4.w};
#pragma unroll
    for (int r = 0; r < 4; ++r) {
      int kk = k0 + kc + r;                 // ascending k: strict < = first-min
#pragma unroll
      for (int p = 0; p < PPT; ++p) {
        // 2*dot with numpy's sequential rounding order (doubling is exact)
        float d = __fmul_rn(z[p][0], c[r].x);
        d = __fadd_rn(d, __fmul_rn(z[p][1], c[r].y));
        d = __fadd_rn(d, __fmul_rn(z[p][2], c[r].z));
        d = __fadd_rn(d, __fmul_rn(z[p][3], c[r].w));
        // ref: (|z|^2 - 2*dot) + |c|^2, left-to-right
        float s = __fadd_rn(__fsub_rn(zz[p], d), cnr[r]);
        if (s < best[p]) { best[p] = s; bidx[p] = kk; }
      }
    }
  }
#pragma unroll
  for (int p = 0; p < PPT; ++p) {
    // pack (sortable float, k): u64 min == (min value, then min k)
    unsigned int u = __float_as_uint(best[p]);
    unsigned int so = (u & 0x80000000u) ? ~u : (u | 0x80000000u);
    unsigned long long key =
        ((unsigned long long)so << 32) | (unsigned int)bidx[p];
    atomicMin(&packed[n0 + 256 * p], key);
  }
}

// ---------------- Kernel F: decode, gather, latent write, loss -------------
__global__ __launch_bounds__(256) void vq_finish(
    const float* __restrict__ ze, const float* __restrict__ w,
    const float* __restrict__ bias, const float* __restrict__ cb,
    const unsigned long long* __restrict__ packed, float* __restrict__ out) {
  int n = blockIdx.x * 256 + threadIdx.x;
  int bidx = (unsigned int)(packed[n] & 0xFFFFFFFFull);
  float4 c = ((const float4*)cb)[bidx];     // bit-exact gather (16B aligned)
  int b = n >> 12, hw = n & 4095;
  float* o = out + b * CHW + hw;
  o[0] = c.x; o[HW] = c.y; o[2 * HW] = c.z; o[3 * HW] = c.w;
  float z[4], zz;
  compute_z(ze, w, bias, n, z, zz);
  float d0 = c.x - z[0], d1 = c.y - z[1], d2 = c.z - z[2], d3 = c.w - z[3];
  float e = d0 * d0 + d1 * d1 + d2 * d2 + d3 * d3;
#pragma unroll
  for (int off = 32; off > 0; off >>= 1) e += __shfl_down(e, off, 64);
  __shared__ float sred[4];
  if ((threadIdx.x & 63) == 0) sred[threadIdx.x >> 6] = e;
  __syncthreads();
  if (threadIdx.x == 0) {
    float t = (sred[0] + sred[1]) + (sred[2] + sred[3]);
    // q_loss = (1 + BETA) * mean over 131072 elements
    atomicAdd(out + (N_POINTS * 4), t * (1.25f / 131072.f));
  }
}

extern "C" void kernel_launch(void* const* d_in, const int* in_sizes, int n_in,
                              void* d_out, int out_size, void* d_ws, size_t ws_size,
                              hipStream_t stream) {
  const float* ze   = (const float*)d_in[0];  // z_e_in [8,4,64,64]
  const float* w    = (const float*)d_in[1];  // pq_w [4,4]
  const float* bias = (const float*)d_in[2];  // pq_b [4]
  const float* cb   = (const float*)d_in[3];  // codebook [8192,4]

  char* ws = (char*)d_ws;
  float4* cb2 = (float4*)(ws + WS_CB2);
  float*  cbn = (float*)(ws + WS_CBN);
  unsigned long long* packed = (unsigned long long*)(ws + WS_PACKED);
  float* out = (float*)d_out;

  vq_init<<<128, 256, 0, stream>>>(cb, cb2, cbn, packed, out);
  vq_scan<<<dim3(N_POINTS / PTILE, NSEG), 256, 0, stream>>>(
      ze, w, bias, cb2, cbn, packed);
  vq_finish<<<128, 256, 0, stream>>>(ze, w, bias, cb, packed, out);
}

// Round 4
// 120.260 us; speedup vs baseline: 1.3948x; 1.1869x over previous
//
#include <hip/hip_runtime.h>
#include <math.h>

// Problem constants (fixed by setup_inputs): B=8, C=4, H=W=64, K=8192
#define N_POINTS 32768   // B*H*W
#define KCODES   8192
#define HW       4096
#define CHW      16384
#define NSEG     64
#define SEGLEN   (KCODES / NSEG)   // 128
#define PPT      8                 // points per thread in vq_scan
#define PTILE    (256 * PPT)       // 2048 points per block

// ws layout (bytes):
//   cb2    float4[8192]  @ 0        (2*codebook — exact doubling)
//   cbn    float [8192]  @ 131072   (|c|^2, numpy rounding order; 16B aligned)
//   packed u64   [32768] @ 163840   ((sortable(best_d2)<<32)|best_k per point)
#define WS_CB2    0
#define WS_CBN    131072
#define WS_PACKED 163840

// Bit-exact conv z = W x + b, numpy sequential c-order, no FMA contraction.
__device__ __forceinline__ void compute_z(
    const float* __restrict__ ze, const float* __restrict__ w,
    const float* __restrict__ bias, int n, float zo[4], float& zz) {
  int b = n >> 12, hw = n & 4095;
  const float* p = ze + b * CHW + hw;
  float x0 = p[0], x1 = p[HW], x2 = p[2 * HW], x3 = p[3 * HW];
#pragma unroll
  for (int o = 0; o < 4; ++o) {
    float acc = __fmul_rn(x0, w[o * 4 + 0]);
    acc = __fadd_rn(acc, __fmul_rn(x1, w[o * 4 + 1]));
    acc = __fadd_rn(acc, __fmul_rn(x2, w[o * 4 + 2]));
    acc = __fadd_rn(acc, __fmul_rn(x3, w[o * 4 + 3]));
    zo[o] = __fadd_rn(acc, bias[o]);
  }
  float s = __fmul_rn(zo[0], zo[0]);
  s = __fadd_rn(s, __fmul_rn(zo[1], zo[1]));
  s = __fadd_rn(s, __fmul_rn(zo[2], zo[2]));
  s = __fadd_rn(s, __fmul_rn(zo[3], zo[3]));
  zz = s;
}

// ---------------- Kernel P: init packed + codebook transform + loss zero ---
__global__ __launch_bounds__(256) void vq_init(
    const float* __restrict__ cb, float4* __restrict__ cb2,
    float* __restrict__ cbn, unsigned long long* __restrict__ packed,
    float* __restrict__ out) {
  int t = blockIdx.x * 256 + threadIdx.x;   // grid covers 32768
  packed[t] = 0xFFFFFFFFFFFFFFFFull;        // ws is re-poisoned every call
  if (t < KCODES) {
    float c0 = cb[t * 4 + 0], c1 = cb[t * 4 + 1];
    float c2 = cb[t * 4 + 2], c3 = cb[t * 4 + 3];
    // doubling by 2 is exact: sum(2*z*c) == 2*sum(z*c) bitwise
    cb2[t] = make_float4(2.f * c0, 2.f * c1, 2.f * c2, 2.f * c3);
    float s = __fmul_rn(c0, c0);
    s = __fadd_rn(s, __fmul_rn(c1, c1));
    s = __fadd_rn(s, __fmul_rn(c2, c2));
    s = __fadd_rn(s, __fmul_rn(c3, c3));
    cbn[t] = s;
  }
  if (t == 0) out[N_POINTS * 4] = 0.f;      // zero the q_loss slot
}

// ---------------- Kernel S: fused conv + argmin scan, register-blocked -----
// Each thread: 8 points in registers, codes streamed in chunks of 4.
// 5 float4 loads serve 32 pair-computations (~12.4 VALU lane-ops/pair).
// (256,4): allow 128 VGPRs — R3's 32-VGPR squeeze serialized the loads.
__global__ __launch_bounds__(256, 4) void vq_scan(
    const float* __restrict__ ze, const float* __restrict__ w,
    const float* __restrict__ bias, const float4* __restrict__ cb2,
    const float* __restrict__ cbn, unsigned long long* __restrict__ packed) {
  int tid = threadIdx.x;
  int n0 = blockIdx.x * PTILE + tid;        // points n0 + 256*p, coalesced
  float z[PPT][4], zz[PPT], best[PPT];
  int bidx[PPT];
#pragma unroll
  for (int p = 0; p < PPT; ++p) {
    compute_z(ze, w, bias, n0 + 256 * p, z[p], zz[p]);
    best[p] = INFINITY;
    bidx[p] = 0;
  }
  int k0 = blockIdx.y * SEGLEN;
  const float4* cp = cb2 + k0;
  const float4* np = (const float4*)(cbn + k0);   // 16B aligned, k0 % 4 == 0
  for (int kc = 0; kc < SEGLEN; kc += 4) {
    float4 c[4];
    c[0] = cp[kc + 0]; c[1] = cp[kc + 1];
    c[2] = cp[kc + 2]; c[3] = cp[kc + 3];
    float4 cn4 = np[kc >> 2];
    float cnr[4] = {cn4.x, cn4.y, cn4.z, cn4.w};
#pragma unroll
    for (int r = 0; r < 4; ++r) {
      int kk = k0 + kc + r;                 // ascending k: strict < = first-min
#pragma unroll
      for (int p = 0; p < PPT; ++p) {
        // 2*dot with numpy's sequential rounding order (doubling is exact)
        float d = __fmul_rn(z[p][0], c[r].x);
        d = __fadd_rn(d, __fmul_rn(z[p][1], c[r].y));
        d = __fadd_rn(d, __fmul_rn(z[p][2], c[r].z));
        d = __fadd_rn(d, __fmul_rn(z[p][3], c[r].w));
        // ref: (|z|^2 - 2*dot) + |c|^2, left-to-right
        float s = __fadd_rn(__fsub_rn(zz[p], d), cnr[r]);
        if (s < best[p]) { best[p] = s; bidx[p] = kk; }
      }
    }
  }
#pragma unroll
  for (int p = 0; p < PPT; ++p) {
    // pack (sortable float, k): u64 min == (min value, then min k)
    unsigned int u = __float_as_uint(best[p]);
    unsigned int so = (u & 0x80000000u) ? ~u : (u | 0x80000000u);
    unsigned long long key =
        ((unsigned long long)so << 32) | (unsigned int)bidx[p];
    atomicMin(&packed[n0 + 256 * p], key);
  }
}

// ---------------- Kernel F: decode, gather, latent write, loss -------------
__global__ __launch_bounds__(256) void vq_finish(
    const float* __restrict__ ze, const float* __restrict__ w,
    const float* __restrict__ bias, const float* __restrict__ cb,
    const unsigned long long* __restrict__ packed, float* __restrict__ out) {
  int n = blockIdx.x * 256 + threadIdx.x;
  int bidx = (unsigned int)(packed[n] & 0xFFFFFFFFull);
  float4 c = ((const float4*)cb)[bidx];     // bit-exact gather (16B aligned)
  int b = n >> 12, hw = n & 4095;
  float* o = out + b * CHW + hw;
  o[0] = c.x; o[HW] = c.y; o[2 * HW] = c.z; o[3 * HW] = c.w;
  float z[4], zz;
  compute_z(ze, w, bias, n, z, zz);
  float d0 = c.x - z[0], d1 = c.y - z[1], d2 = c.z - z[2], d3 = c.w - z[3];
  float e = d0 * d0 + d1 * d1 + d2 * d2 + d3 * d3;
#pragma unroll
  for (int off = 32; off > 0; off >>= 1) e += __shfl_down(e, off, 64);
  __shared__ float sred[4];
  if ((threadIdx.x & 63) == 0) sred[threadIdx.x >> 6] = e;
  __syncthreads();
  if (threadIdx.x == 0) {
    float t = (sred[0] + sred[1]) + (sred[2] + sred[3]);
    // q_loss = (1 + BETA) * mean over 131072 elements
    atomicAdd(out + (N_POINTS * 4), t * (1.25f / 131072.f));
  }
}

extern "C" void kernel_launch(void* const* d_in, const int* in_sizes, int n_in,
                              void* d_out, int out_size, void* d_ws, size_t ws_size,
                              hipStream_t stream) {
  const float* ze   = (const float*)d_in[0];  // z_e_in [8,4,64,64]
  const float* w    = (const float*)d_in[1];  // pq_w [4,4]
  const float* bias = (const float*)d_in[2];  // pq_b [4]
  const float* cb   = (const float*)d_in[3];  // codebook [8192,4]

  char* ws = (char*)d_ws;
  float4* cb2 = (float4*)(ws + WS_CB2);
  float*  cbn = (float*)(ws + WS_CBN);
  unsigned long long* packed = (unsigned long long*)(ws + WS_PACKED);
  float* out = (float*)d_out;

  vq_init<<<128, 256, 0, stream>>>(cb, cb2, cbn, packed, out);
  vq_scan<<<dim3(N_POINTS / PTILE, NSEG), 256, 0, stream>>>(
      ze, w, bias, cb2, cbn, packed);
  vq_finish<<<128, 256, 0, stream>>>(ze, w, bias, cb, packed, out);
}

// Round 5
// 119.440 us; speedup vs baseline: 1.4043x; 1.0069x over previous
//
#include <hip/hip_runtime.h>
#include <math.h>

// Problem constants (fixed by setup_inputs): B=8, C=4, H=W=64, K=8192
#define N_POINTS 32768   // B*H*W
#define KCODES   8192
#define HW       4096
#define CHW      16384
#define NSEG     128
#define SEGLEN   (KCODES / NSEG)   // 64
#define PPT      8                 // points per thread in vq_scan
#define PTILE    (256 * PPT)       // 2048 points per block

// ws layout (bytes):
//   cb2    float4[8192]  @ 0        (2*codebook — exact doubling)
//   cbn    float [8192]  @ 131072   (|c|^2, numpy rounding order; 16B aligned)
//   packed u64   [32768] @ 163840   ((sortable(best_d2)<<32)|best_k per point)
#define WS_CB2    0
#define WS_CBN    131072
#define WS_PACKED 163840

// Bit-exact conv z = W x + b, numpy sequential c-order, no FMA contraction.
__device__ __forceinline__ void compute_z(
    const float* __restrict__ ze, const float* __restrict__ w,
    const float* __restrict__ bias, int n, float zo[4], float& zz) {
  int b = n >> 12, hw = n & 4095;
  const float* p = ze + b * CHW + hw;
  float x0 = p[0], x1 = p[HW], x2 = p[2 * HW], x3 = p[3 * HW];
#pragma unroll
  for (int o = 0; o < 4; ++o) {
    float acc = __fmul_rn(x0, w[o * 4 + 0]);
    acc = __fadd_rn(acc, __fmul_rn(x1, w[o * 4 + 1]));
    acc = __fadd_rn(acc, __fmul_rn(x2, w[o * 4 + 2]));
    acc = __fadd_rn(acc, __fmul_rn(x3, w[o * 4 + 3]));
    zo[o] = __fadd_rn(acc, bias[o]);
  }
  float s = __fmul_rn(zo[0], zo[0]);
  s = __fadd_rn(s, __fmul_rn(zo[1], zo[1]));
  s = __fadd_rn(s, __fmul_rn(zo[2], zo[2]));
  s = __fadd_rn(s, __fmul_rn(zo[3], zo[3]));
  zz = s;
}

// ---------------- Kernel P: init packed + codebook transform + loss zero ---
__global__ __launch_bounds__(256) void vq_init(
    const float* __restrict__ cb, float4* __restrict__ cb2,
    float* __restrict__ cbn, unsigned long long* __restrict__ packed,
    float* __restrict__ out) {
  int t = blockIdx.x * 256 + threadIdx.x;   // grid covers 32768
  packed[t] = 0xFFFFFFFFFFFFFFFFull;        // ws is re-poisoned every call
  if (t < KCODES) {
    float c0 = cb[t * 4 + 0], c1 = cb[t * 4 + 1];
    float c2 = cb[t * 4 + 2], c3 = cb[t * 4 + 3];
    // doubling by 2 is exact: sum(2*z*c) == 2*sum(z*c) bitwise
    cb2[t] = make_float4(2.f * c0, 2.f * c1, 2.f * c2, 2.f * c3);
    float s = __fmul_rn(c0, c0);
    s = __fadd_rn(s, __fmul_rn(c1, c1));
    s = __fadd_rn(s, __fmul_rn(c2, c2));
    s = __fadd_rn(s, __fmul_rn(c3, c3));
    cbn[t] = s;
  }
  if (t == 0) out[N_POINTS * 4] = 0.f;      // zero the q_loss slot
}

// ---------------- Kernel S: fused conv + argmin scan, register-blocked -----
// Each thread: 8 points in registers, codes streamed in chunks of 4.
// 5 float4 loads serve 32 pair-computations (~12.4 VALU lane-ops/pair).
// VGPR=64 (measured) -> 8 waves/SIMD capacity; grid gives 8 blocks/CU.
__global__ __launch_bounds__(256, 4) void vq_scan(
    const float* __restrict__ ze, const float* __restrict__ w,
    const float* __restrict__ bias, const float4* __restrict__ cb2,
    const float* __restrict__ cbn, unsigned long long* __restrict__ packed) {
  int tid = threadIdx.x;
  int n0 = blockIdx.x * PTILE + tid;        // points n0 + 256*p, coalesced
  float z[PPT][4], zz[PPT], best[PPT];
  int bidx[PPT];
#pragma unroll
  for (int p = 0; p < PPT; ++p) {
    compute_z(ze, w, bias, n0 + 256 * p, z[p], zz[p]);
    best[p] = INFINITY;
    bidx[p] = 0;
  }
  int k0 = blockIdx.y * SEGLEN;
  const float4* cp = cb2 + k0;
  const float4* np = (const float4*)(cbn + k0);   // 16B aligned, k0 % 4 == 0
  for (int kc = 0; kc < SEGLEN; kc += 4) {
    float4 c[4];
    c[0] = cp[kc + 0]; c[1] = cp[kc + 1];
    c[2] = cp[kc + 2]; c[3] = cp[kc + 3];
    float4 cn4 = np[kc >> 2];
    float cnr[4] = {cn4.x, cn4.y, cn4.z, cn4.w};
#pragma unroll
    for (int r = 0; r < 4; ++r) {
      int kk = k0 + kc + r;                 // ascending k: strict < = first-min
#pragma unroll
      for (int p = 0; p < PPT; ++p) {
        // 2*dot with numpy's sequential rounding order (doubling is exact)
        float d = __fmul_rn(z[p][0], c[r].x);
        d = __fadd_rn(d, __fmul_rn(z[p][1], c[r].y));
        d = __fadd_rn(d, __fmul_rn(z[p][2], c[r].z));
        d = __fadd_rn(d, __fmul_rn(z[p][3], c[r].w));
        // ref: (|z|^2 - 2*dot) + |c|^2, left-to-right
        float s = __fadd_rn(__fsub_rn(zz[p], d), cnr[r]);
        if (s < best[p]) { best[p] = s; bidx[p] = kk; }
      }
    }
  }
#pragma unroll
  for (int p = 0; p < PPT; ++p) {
    // pack (sortable float, k): u64 min == (min value, then min k)
    unsigned int u = __float_as_uint(best[p]);
    unsigned int so = (u & 0x80000000u) ? ~u : (u | 0x80000000u);
    unsigned long long key =
        ((unsigned long long)so << 32) | (unsigned int)bidx[p];
    atomicMin(&packed[n0 + 256 * p], key);
  }
}

// ---------------- Kernel F: decode, gather, latent write, loss -------------
__global__ __launch_bounds__(256) void vq_finish(
    const float* __restrict__ ze, const float* __restrict__ w,
    const float* __restrict__ bias, const float* __restrict__ cb,
    const unsigned long long* __restrict__ packed, float* __restrict__ out) {
  int n = blockIdx.x * 256 + threadIdx.x;
  int bidx = (unsigned int)(packed[n] & 0xFFFFFFFFull);
  float4 c = ((const float4*)cb)[bidx];     // bit-exact gather (16B aligned)
  int b = n >> 12, hw = n & 4095;
  float* o = out + b * CHW + hw;
  o[0] = c.x; o[HW] = c.y; o[2 * HW] = c.z; o[3 * HW] = c.w;
  float z[4], zz;
  compute_z(ze, w, bias, n, z, zz);
  float d0 = c.x - z[0], d1 = c.y - z[1], d2 = c.z - z[2], d3 = c.w - z[3];
  float e = d0 * d0 + d1 * d1 + d2 * d2 + d3 * d3;
#pragma unroll
  for (int off = 32; off > 0; off >>= 1) e += __shfl_down(e, off, 64);
  __shared__ float sred[4];
  if ((threadIdx.x & 63) == 0) sred[threadIdx.x >> 6] = e;
  __syncthreads();
  if (threadIdx.x == 0) {
    float t = (sred[0] + sred[1]) + (sred[2] + sred[3]);
    // q_loss = (1 + BETA) * mean over 131072 elements
    atomicAdd(out + (N_POINTS * 4), t * (1.25f / 131072.f));
  }
}

extern "C" void kernel_launch(void* const* d_in, const int* in_sizes, int n_in,
                              void* d_out, int out_size, void* d_ws, size_t ws_size,
                              hipStream_t stream) {
  const float* ze   = (const float*)d_in[0];  // z_e_in [8,4,64,64]
  const float* w    = (const float*)d_in[1];  // pq_w [4,4]
  const float* bias = (const float*)d_in[2];  // pq_b [4]
  const float* cb   = (const float*)d_in[3];  // codebook [8192,4]

  char* ws = (char*)d_ws;
  float4* cb2 = (float4*)(ws + WS_CB2);
  float*  cbn = (float*)(ws + WS_CBN);
  unsigned long long* packed = (unsigned long long*)(ws + WS_PACKED);
  float* out = (float*)d_out;

  vq_init<<<128, 256, 0, stream>>>(cb, cb2, cbn, packed, out);
  vq_scan<<<dim3(N_POINTS / PTILE, NSEG), 256, 0, stream>>>(
      ze, w, bias, cb2, cbn, packed);
  vq_finish<<<128, 256, 0, stream>>>(ze, w, bias, cb, packed, out);
}